// Round 12
// baseline (423.464 us; speedup 1.0000x reference)
//
#include <hip/hip_runtime.h>
#include <hip/hip_fp16.h>

#define NEG_SLOPE 0.2f
#define LOG2E 1.4426950408889634f

typedef _Float16 half4v __attribute__((ext_vector_type(4)));
typedef _Float16 half8v __attribute__((ext_vector_type(8)));
typedef float f32x4 __attribute__((ext_vector_type(4)));

// ---------------------------------------------------------------------------
// float<->ordered-uint encoding for atomicMax on floats
// ---------------------------------------------------------------------------
__device__ inline unsigned enc_max(float f) {
    unsigned b = __float_as_uint(f);
    return (b & 0x80000000u) ? ~b : (b | 0x80000000u);
}
__device__ inline float dec_max(unsigned k) {
    return (k & 0x80000000u) ? __uint_as_float(k ^ 0x80000000u)
                             : __uint_as_float(~k);
}

// ---------------------------------------------------------------------------
// One-time W pre-transpose: Wt[layer][c][k] = fp16(W[k][c]).  2 x 32 KB.
// ---------------------------------------------------------------------------
__global__ void wprep_kernel(const float* __restrict__ W1,
                             const float* __restrict__ W2,
                             _Float16* __restrict__ Wt)
{
    const int idx = blockIdx.x * 256 + threadIdx.x;   // [0, 32768)
    const float* W = (idx < 16384) ? W1 : W2;
    const int i = idx & 16383;
    const int c = i >> 7, k = i & 127;
    Wt[idx] = (_Float16)W[k * 128 + c];
}

// ---------------------------------------------------------------------------
// MFMA GEMM + attention projections.
//   H16[r,:] = fp16(X[r,:] @ W); AL[r] = (als_h0, als_h1, ald_h0, ald_h1)
// AL PRE-SCALED by log2(e). W^T staged from pre-transposed fp16 Wt with
// coalesced uint4 loads (swizzled 16B slots). X staged fp32->fp16 swizzled.
// Block = 256 thr = 4 waves, 64 rows, v_mfma_f32_16x16x16f16 x 8 col-tiles.
// ---------------------------------------------------------------------------
__global__ __launch_bounds__(256) void gemm_al_kernel(
    const float* __restrict__ X, const _Float16* __restrict__ Wt,
    const float* __restrict__ asrc, const float* __restrict__ adst,
    __half* __restrict__ H16, float* __restrict__ AL,
    unsigned* __restrict__ ubp, int N)
{
    __shared__ alignas(16) char smem[49152];

    const int t = threadIdx.x, lane = t & 63, wave = t >> 6;
    const int r0 = blockIdx.x * 64;

    // ---- stage X (fp32 -> fp16, swizzled 16B slots) ----
#pragma unroll
    for (int i = 0; i < 8; i++) {
        const int f = t + i * 256;
        const int row = f >> 5, k4 = f & 31;
        const int k8 = k4 >> 1, hf = k4 & 1;
        float4 v = make_float4(0.f, 0.f, 0.f, 0.f);
        if (r0 + row < N) v = ((const float4*)X)[(size_t)(r0 + row) * 32 + k4];
        half4v h = { (_Float16)v.x, (_Float16)v.y, (_Float16)v.z, (_Float16)v.w };
        const int slot = row * 16 + (k8 ^ (row & 7));
        *(half4v*)(smem + slot * 16 + hf * 8) = h;
    }
    // ---- stage W^T (coalesced uint4 from Wt, swizzled) ----
    {
        const uint4* Wg = (const uint4*)Wt;    // 2048 uint4 = [c][k8]
        uint4* Wl = (uint4*)(smem + 16384);
#pragma unroll
        for (int i = 0; i < 8; i++) {
            const int idx = t + i * 256;
            const int c = idx >> 4, k8 = idx & 15;
            Wl[c * 16 + (k8 ^ (c & 7))] = Wg[idx];
        }
    }
    __syncthreads();

    // ---- MFMA ----
    const int mrow = wave * 16 + (lane & 15);
    const int kg = lane >> 4;
    half4v a[8];
#pragma unroll
    for (int ks = 0; ks < 8; ks++) {
        const int k0 = ks * 16 + kg * 4;
        const int slot = mrow * 16 + ((k0 >> 3) ^ (mrow & 7));
        a[ks] = *(const half4v*)(smem + slot * 16 + (k0 & 7) * 2);
    }
    f32x4 acc[8];
#pragma unroll
    for (int ct = 0; ct < 8; ct++) acc[ct] = (f32x4){0.f, 0.f, 0.f, 0.f};
#pragma unroll
    for (int ct = 0; ct < 8; ct++) {
        const int c = ct * 16 + (lane & 15);
        const char* sbase = smem + 16384 + c * 256;
        const int csw = c & 7;
#pragma unroll
        for (int ks = 0; ks < 8; ks++) {
            const int k0 = ks * 16 + kg * 4;
            const int slot = (k0 >> 3) ^ csw;
            half4v b = *(const half4v*)(sbase + slot * 16 + (k0 & 7) * 2);
            acc[ct] = __builtin_amdgcn_mfma_f32_16x16x16f16(a[ks], b, acc[ct], 0, 0, 0);
        }
    }

    // ---- AL projections (pre-scaled by log2e) + per-head max ----
    float psh0[4] = {0,0,0,0}, psh1[4] = {0,0,0,0};
    float pdh0[4] = {0,0,0,0}, pdh1[4] = {0,0,0,0};
#pragma unroll
    for (int ct = 0; ct < 8; ct++) {
        const int c = ct * 16 + (lane & 15);
        const float as = asrc[c] * LOG2E, ad = adst[c] * LOG2E;
#pragma unroll
        for (int r = 0; r < 4; r++) {
            if (ct < 4) { psh0[r] = fmaf(acc[ct][r], as, psh0[r]);
                          pdh0[r] = fmaf(acc[ct][r], ad, pdh0[r]); }
            else        { psh1[r] = fmaf(acc[ct][r], as, psh1[r]);
                          pdh1[r] = fmaf(acc[ct][r], ad, pdh1[r]); }
        }
    }
#pragma unroll
    for (int off = 1; off <= 8; off <<= 1) {
#pragma unroll
        for (int r = 0; r < 4; r++) {
            psh0[r] += __shfl_xor(psh0[r], off, 64);
            psh1[r] += __shfl_xor(psh1[r], off, 64);
            pdh0[r] += __shfl_xor(pdh0[r], off, 64);
            pdh1[r] += __shfl_xor(pdh1[r], off, 64);
        }
    }
    float rmax0 = -__builtin_inff(), rmax1 = -__builtin_inff();
    if ((lane & 15) == 0) {
#pragma unroll
        for (int r = 0; r < 4; r++) {
            const int gr = r0 + wave * 16 + (lane >> 4) * 4 + r;
            if (gr < N) {
                ((float4*)AL)[gr] = make_float4(psh0[r], psh1[r], pdh0[r], pdh1[r]);
                rmax0 = fmaxf(rmax0, psh0[r]);
                rmax1 = fmaxf(rmax1, psh1[r]);
            }
        }
    }
#pragma unroll
    for (int off = 32; off > 0; off >>= 1) {
        rmax0 = fmaxf(rmax0, __shfl_xor(rmax0, off, 64));
        rmax1 = fmaxf(rmax1, __shfl_xor(rmax1, off, 64));
    }

    // ---- D -> LDS (reuse staging), then coalesced fp16 write ----
    __syncthreads();
    float* Dst = (float*)smem;
    float* red = (float*)(smem + 33792);
    if (lane == 0) { red[wave * 2] = rmax0; red[wave * 2 + 1] = rmax1; }
#pragma unroll
    for (int ct = 0; ct < 8; ct++) {
        const int col = ct * 16 + (lane & 15);
        float* drow = Dst + wave * 2112 + ((lane >> 4) * 4) * 132 + col;
#pragma unroll
        for (int r = 0; r < 4; r++) drow[r * 132] = acc[ct][r];
    }
    __syncthreads();
    if (t < 2) {
        float m = fmaxf(fmaxf(red[t], red[2 + t]), fmaxf(red[4 + t], red[6 + t]));
        atomicMax(&ubp[t], enc_max(m));
    }
#pragma unroll
    for (int i = 0; i < 4; i++) {
        const int f = t + i * 256;
        const int row = f >> 4, c16 = f & 15;
        if (r0 + row < N) {
            const float* src = Dst + (row >> 4) * 2112 + (row & 15) * 132 + c16 * 8;
            const float4 v0 = *(const float4*)src;
            const float4 v1 = *(const float4*)(src + 4);
            half8v h = { (_Float16)v0.x, (_Float16)v0.y, (_Float16)v0.z, (_Float16)v0.w,
                         (_Float16)v1.x, (_Float16)v1.y, (_Float16)v1.z, (_Float16)v1.w };
            *(half8v*)((_Float16*)H16 + (size_t)(r0 + row) * 128 + c16 * 8) = h;
        }
    }
}

// ---------------------------------------------------------------------------
// Edge-weight precompute: p2[e] = (p_h0, p_h1), full-SIMD (1 lane per node).
// p = exp2(leaky(als + ald) - ub) in exp2 domain (AL pre-scaled by log2e).
// ---------------------------------------------------------------------------
__global__ void pw_kernel(const float* __restrict__ AL,
                          const int* __restrict__ dstptr,
                          const int* __restrict__ ssrc,
                          const unsigned* __restrict__ ubenc,
                          float2* __restrict__ p2, int N)
{
    const int n = blockIdx.x * 256 + threadIdx.x;
    if (n >= N) return;
    const int beg = dstptr[n], end = dstptr[n + 1];
    const float ald0 = AL[(size_t)n * 4 + 2];
    const float ald1 = AL[(size_t)n * 4 + 3];
    float u0 = dec_max(ubenc[0]) + ald0; u0 = fmaxf(u0, NEG_SLOPE * u0);
    float u1 = dec_max(ubenc[1]) + ald1; u1 = fmaxf(u1, NEG_SLOPE * u1);
    for (int e = beg; e < end; e++) {
        const int s = ssrc[e];
        float a0 = AL[(size_t)s * 4 + 0] + ald0; a0 = fmaxf(a0, NEG_SLOPE * a0);
        float a1 = AL[(size_t)s * 4 + 1] + ald1; a1 = fmaxf(a1, NEG_SLOPE * a1);
        p2[e] = make_float2(exp2f(a0 - u0), exp2f(a1 - u1));
    }
}

// ---------------------------------------------------------------------------
// CSR build: sliced count -> scan -> finalize -> sliced scatter.
// ---------------------------------------------------------------------------
__global__ void count_kernel(const int* __restrict__ edst, int* __restrict__ cnt,
                             int E, int N, int sliceN, int bps)
{
    const int slice = blockIdx.x & 7;
    const int dlo = slice * sliceN;
    const int dhi = min(N, dlo + sliceN);
    const int Etot = E + N;
    for (int i = (blockIdx.x >> 3) * 256 + (int)threadIdx.x; i < Etot; i += bps * 256) {
        const int d = (i < E) ? edst[i] : (i - E);
        if (d >= dlo && d < dhi) atomicAdd(&cnt[d], 1);
    }
}

__global__ void scan_local_kernel(const int* __restrict__ in, int* __restrict__ out,
                                  int* __restrict__ bsum, int n)
{
    __shared__ int sm[1024];
    const int t = threadIdx.x;
    const int i = blockIdx.x * 1024 + t;
    int v = (i < n) ? in[i] : 0;
    sm[t] = v;
    __syncthreads();
    for (int off = 1; off < 1024; off <<= 1) {
        int x = (t >= off) ? sm[t - off] : 0;
        __syncthreads();
        sm[t] += x;
        __syncthreads();
    }
    if (i < n) out[i] = sm[t];
    if (t == 1023) bsum[blockIdx.x] = sm[t];
}

__global__ void scan_excl_single_kernel(int* __restrict__ a, int B)
{
    __shared__ int sm[1024];
    const int t = threadIdx.x;
    int v = (t < B) ? a[t] : 0;
    sm[t] = v;
    __syncthreads();
    for (int off = 1; off < 1024; off <<= 1) {
        int x = (t >= off) ? sm[t - off] : 0;
        __syncthreads();
        sm[t] += x;
        __syncthreads();
    }
    if (t < B) a[t] = sm[t] - v;   // exclusive
}

__global__ void finalize_csr_kernel(const int* __restrict__ incl,
                                    const int* __restrict__ cnt,
                                    const int* __restrict__ bexcl,
                                    int* __restrict__ dstptr, int* __restrict__ cursor,
                                    int N, int Etot)
{
    const int i = blockIdx.x * 1024 + threadIdx.x;
    if (i < N) {
        int v = incl[i] + bexcl[i >> 10] - cnt[i];
        dstptr[i] = v;
        cursor[i] = v;
    }
    if (i == N) dstptr[N] = Etot;
}

__global__ void scatter_kernel(const int* __restrict__ esrc, const int* __restrict__ edst,
                               int* __restrict__ cursor, int* __restrict__ ssrc,
                               int E, int N, int sliceN, int bps)
{
    const int slice = blockIdx.x & 7;
    const int dlo = slice * sliceN;
    const int dhi = min(N, dlo + sliceN);
    const int Etot = E + N;
    for (int i = (blockIdx.x >> 3) * 256 + (int)threadIdx.x; i < Etot; i += bps * 256) {
        int s, d;
        if (i < E) { s = esrc[i]; d = edst[i]; }
        else       { s = d = i - E; }
        if (d >= dlo && d < dhi) {
            int pos = atomicAdd(&cursor[d], 1);
            ssrc[pos] = s;
        }
    }
}

// ---------------------------------------------------------------------------
// Aggregation using precomputed p. TWO nodes per wave (lanes 0-31 node A,
// 32-63 node B); lane owns 4 channels (uint2 = 8B gathers); head = nl>>4.
// Per edge: broadcast p load + one h16 gather + 4 fma. Mov-free 3-slot ring.
// mode 0: out[n,128] = ELU(acc/s + b)   mode 1: out[n,64] = mean_h(acc/s)+b
// ---------------------------------------------------------------------------
__global__ __launch_bounds__(256) void aggregate_kernel(
    const __half* __restrict__ H16, const float* __restrict__ pw,
    const int* __restrict__ dstptr, const int* __restrict__ ssrc,
    const float* __restrict__ bias, float* __restrict__ out, int N, int mode)
{
    const int wid  = (blockIdx.x * blockDim.x + threadIdx.x) >> 6;
    const int lane = threadIdx.x & 63;
    if (wid * 2 >= N) return;
    const int n    = wid * 2 + (lane >> 5);
    const bool act = (n < N);
    const int nn   = act ? n : (N - 1);
    const int beg  = dstptr[nn];
    const int edges = act ? (dstptr[nn + 1] - beg) : 0;
    const int nl   = lane & 31;
    const int head = nl >> 4;
    const float* ph = pw + head;              // p[e*2 + head]

    int tr = (edges + 3) >> 2;
    tr = max(tr, __shfl_xor(tr, 32, 64));
    const int trips = tr;

    float s = 0.f, a0 = 0.f, a1 = 0.f, a2 = 0.f, a3 = 0.f;

    int   sv0[4], sv1[4], sv2[4];
    float e0[4], e1[4], e2[4];
    uint2 g0[4], g1[4], g2[4];

    auto LSRC = [&](int b, int (&sv)[4]) {
#pragma unroll
        for (int k = 0; k < 4; k++) {
            const int idx = 4 * b + k;
            const int v = ssrc[beg + idx];    // padded: safe
            sv[k] = (idx < edges) ? v : 0;    // clamp masked -> hot row 0
        }
    };
    auto LHE = [&](int b, const int (&sv)[4], float (&e)[4], uint2 (&g)[4]) {
#pragma unroll
        for (int k = 0; k < 4; k++) {
            e[k] = ph[2 * (beg + 4 * b + k)]; // broadcast, padded: safe
            g[k] = ((const uint2*)(H16 + (size_t)sv[k] * 128))[nl];
        }
    };
    auto COMP = [&](int t, const float (&e)[4], const uint2 (&g)[4]) {
        const int rem = edges - 4 * t;        // <=0 for overflow/inactive
#pragma unroll
        for (int k = 0; k < 4; k++) {
            const float p = (k < rem) ? e[k] : 0.f;
            s += p;
            const __half2* hh = (const __half2*)&g[k];
            const float2 f01 = __half22float2(hh[0]);
            const float2 f23 = __half22float2(hh[1]);
            a0 = fmaf(p, f01.x, a0);
            a1 = fmaf(p, f01.y, a1);
            a2 = fmaf(p, f23.x, a2);
            a3 = fmaf(p, f23.y, a3);
        }
    };

    // prologue: srcs for blocks 0..2; p+h for blocks 0,1 in flight
    LSRC(0, sv0); LSRC(1, sv1); LSRC(2, sv2);
    LHE(0, sv0, e0, g0);
    LHE(1, sv1, e1, g1);

    for (int t = 0; t < trips; ) {
        LHE(t + 2, sv2, e2, g2); LSRC(t + 3, sv0); COMP(t, e0, g0); if (++t == trips) break;
        LHE(t + 2, sv0, e0, g0); LSRC(t + 3, sv1); COMP(t, e1, g1); if (++t == trips) break;
        LHE(t + 2, sv1, e1, g1); LSRC(t + 3, sv2); COMP(t, e2, g2); if (++t == trips) break;
    }

    if (!act) return;
    const float inv = 1.f / s;                // s > 0 (self loop)
    float o0 = a0 * inv, o1 = a1 * inv, o2 = a2 * inv, o3 = a3 * inv;

    if (mode == 0) {
        const float4 b4 = ((const float4*)bias)[nl];
        o0 += b4.x; o1 += b4.y; o2 += b4.z; o3 += b4.w;
        o0 = (o0 > 0.f) ? o0 : (__expf(o0) - 1.f);
        o1 = (o1 > 0.f) ? o1 : (__expf(o1) - 1.f);
        o2 = (o2 > 0.f) ? o2 : (__expf(o2) - 1.f);
        o3 = (o3 > 0.f) ? o3 : (__expf(o3) - 1.f);
        ((float4*)out)[(size_t)n * 32 + nl] = make_float4(o0, o1, o2, o3);
    } else {
        const float q0 = __shfl_xor(o0, 16, 64);   // head partner within node
        const float q1 = __shfl_xor(o1, 16, 64);
        const float q2 = __shfl_xor(o2, 16, 64);
        const float q3 = __shfl_xor(o3, 16, 64);
        if (nl < 16) {
            const float4 b4 = ((const float4*)bias)[nl];
            ((float4*)out)[(size_t)n * 16 + nl] =
                make_float4(0.5f * (o0 + q0) + b4.x, 0.5f * (o1 + q1) + b4.y,
                            0.5f * (o2 + q2) + b4.z, 0.5f * (o3 + q3) + b4.w);
        }
    }
}

// ---------------------------------------------------------------------------
extern "C" void kernel_launch(void* const* d_in, const int* in_sizes, int n_in,
                              void* d_out, int out_size, void* d_ws, size_t ws_size,
                              hipStream_t stream)
{
    const float* x   = (const float*)d_in[0];
    const int*   eix = (const int*)d_in[1];   // [2, E] int32
    const float* W1  = (const float*)d_in[2];
    const float* as1 = (const float*)d_in[3];
    const float* ad1 = (const float*)d_in[4];
    const float* b1  = (const float*)d_in[5];
    const float* W2  = (const float*)d_in[6];
    const float* as2 = (const float*)d_in[7];
    const float* ad2 = (const float*)d_in[8];
    const float* b2  = (const float*)d_in[9];
    float* out = (float*)d_out;

    const int N = in_sizes[0] / 128;
    const int E = in_sizes[1] / 2;
    const int Etot = E + N;
    const int* esrc = eix;
    const int* edst = eix + E;

    // ---- workspace layout (~101 MB) ----
    char* p = (char*)d_ws;
    __half*    h16    = (__half*)p;    p += (size_t)N * 128 * 2;
    float*     y1     = (float*)p;     p += (size_t)N * 128 * 4;
    float*     al     = (float*)p;     p += (size_t)N * 4 * 4;
    int*       cnt    = (int*)p;       p += (size_t)N * 4;
    unsigned*  ub     = (unsigned*)p;  p += 64;                // [0..1] L1, [2..3] L2
    _Float16*  wt     = (_Float16*)p;  p += 32768 * 2;         // 2 layers W^T fp16
    int*       incl   = (int*)p;       p += (size_t)N * 4;
    int*       dstptr = (int*)p;       p += (size_t)(N + 1) * 4;
    int*       cursor = (int*)p;       p += (size_t)N * 4;
    int*       bs1    = (int*)p;       p += 1024 * 4;
    float2*    p2     = (float2*)p;    p += (size_t)(Etot + 1024) * 8;
    int*       ssrc   = (int*)p;       p += (size_t)(Etot + 1024) * 4;

    hipMemsetAsync(cnt, 0, (size_t)N * 4 + 64, stream);      // cnt + ub
    hipMemsetAsync(ssrc + Etot, 0, 1024 * 4, stream);        // zero tail pad

    // ---- one-time prep + CSR (shared by both layers) ----
    wprep_kernel<<<128, 256, 0, stream>>>(W1, W2, wt);
    {
        const int B0 = (N + 1023) / 1024;
        const int sliceN = (N + 7) / 8;
        const int bps = 512;
        count_kernel<<<bps * 8, 256, 0, stream>>>(edst, cnt, E, N, sliceN, bps);
        scan_local_kernel<<<B0, 1024, 0, stream>>>(cnt, incl, bs1, N);
        scan_excl_single_kernel<<<1, 1024, 0, stream>>>(bs1, B0);
        finalize_csr_kernel<<<(N + 1024) / 1024, 1024, 0, stream>>>(
            incl, cnt, bs1, dstptr, cursor, N, Etot);
        scatter_kernel<<<bps * 8, 256, 0, stream>>>(esrc, edst, cursor, ssrc,
                                                    E, N, sliceN, bps);
    }

    const int ggrid = (N + 63) / 64;                   // 64 rows/block (MFMA)
    const int pblocks = (N + 255) / 256;
    const int ablocks = (N + 7) / 8;                   // 8 nodes per 256-thr block

    // ---- Layer 1 ----
    gemm_al_kernel<<<ggrid, 256, 0, stream>>>(x, wt, as1, ad1, h16, al, ub, N);
    pw_kernel<<<pblocks, 256, 0, stream>>>(al, dstptr, ssrc, ub, p2, N);
    aggregate_kernel<<<ablocks, 256, 0, stream>>>(h16, (const float*)p2, dstptr,
                                                  ssrc, b1, y1, N, 0);

    // ---- Layer 2 ----
    gemm_al_kernel<<<ggrid, 256, 0, stream>>>(y1, wt + 16384, as2, ad2, h16, al, ub + 2, N);
    pw_kernel<<<pblocks, 256, 0, stream>>>(al, dstptr, ssrc, ub + 2, p2, N);
    aggregate_kernel<<<ablocks, 256, 0, stream>>>(h16, (const float*)p2, dstptr,
                                                  ssrc, b2, out, N, 1);
}

// Round 14
// 395.749 us; speedup vs baseline: 1.0700x; 1.0700x over previous
//
#include <hip/hip_runtime.h>
#include <hip/hip_fp16.h>

#define NEG_SLOPE 0.2f
#define LOG2E 1.4426950408889634f

typedef _Float16 half4v __attribute__((ext_vector_type(4)));
typedef _Float16 half8v __attribute__((ext_vector_type(8)));
typedef float f32x4 __attribute__((ext_vector_type(4)));
typedef int i32x4 __attribute__((ext_vector_type(4)));   // clang vector: OK for nontemporal builtins

// ---------------------------------------------------------------------------
// float<->ordered-uint encoding for atomicMax on floats
// ---------------------------------------------------------------------------
__device__ inline unsigned enc_max(float f) {
    unsigned b = __float_as_uint(f);
    return (b & 0x80000000u) ? ~b : (b | 0x80000000u);
}
__device__ inline float dec_max(unsigned k) {
    return (k & 0x80000000u) ? __uint_as_float(k ^ 0x80000000u)
                             : __uint_as_float(~k);
}

// ---------------------------------------------------------------------------
// One-time W pre-transpose: Wt[layer][c][k] = fp16(W[k][c]).  2 x 32 KB.
// ---------------------------------------------------------------------------
__global__ void wprep_kernel(const float* __restrict__ W1,
                             const float* __restrict__ W2,
                             _Float16* __restrict__ Wt)
{
    const int idx = blockIdx.x * 256 + threadIdx.x;   // [0, 32768)
    const float* W = (idx < 16384) ? W1 : W2;
    const int i = idx & 16383;
    const int c = i >> 7, k = i & 127;
    Wt[idx] = (_Float16)W[k * 128 + c];
}

// ---------------------------------------------------------------------------
// MFMA GEMM + attention projections.
//   H16[r,:] = fp16(X[r,:] @ W); AL[r] = (als_h0, als_h1, ald_h0, ald_h1)
// AL PRE-SCALED by log2(e). W^T staged from pre-transposed fp16 Wt with
// coalesced uint4 loads (swizzled 16B slots). X staged fp32->fp16 swizzled.
// Block = 256 thr = 4 waves, 64 rows, v_mfma_f32_16x16x16f16 x 8 col-tiles.
// ---------------------------------------------------------------------------
__global__ __launch_bounds__(256) void gemm_al_kernel(
    const float* __restrict__ X, const _Float16* __restrict__ Wt,
    const float* __restrict__ asrc, const float* __restrict__ adst,
    __half* __restrict__ H16, float* __restrict__ AL,
    unsigned* __restrict__ ubp, int N)
{
    __shared__ alignas(16) char smem[49152];

    const int t = threadIdx.x, lane = t & 63, wave = t >> 6;
    const int r0 = blockIdx.x * 64;

    // ---- stage X (fp32 -> fp16, swizzled 16B slots) ----
#pragma unroll
    for (int i = 0; i < 8; i++) {
        const int f = t + i * 256;
        const int row = f >> 5, k4 = f & 31;
        const int k8 = k4 >> 1, hf = k4 & 1;
        float4 v = make_float4(0.f, 0.f, 0.f, 0.f);
        if (r0 + row < N) v = ((const float4*)X)[(size_t)(r0 + row) * 32 + k4];
        half4v h = { (_Float16)v.x, (_Float16)v.y, (_Float16)v.z, (_Float16)v.w };
        const int slot = row * 16 + (k8 ^ (row & 7));
        *(half4v*)(smem + slot * 16 + hf * 8) = h;
    }
    // ---- stage W^T (coalesced uint4 from Wt, swizzled) ----
    {
        const uint4* Wg = (const uint4*)Wt;    // 2048 uint4 = [c][k8]
        uint4* Wl = (uint4*)(smem + 16384);
#pragma unroll
        for (int i = 0; i < 8; i++) {
            const int idx = t + i * 256;
            const int c = idx >> 4, k8 = idx & 15;
            Wl[c * 16 + (k8 ^ (c & 7))] = Wg[idx];
        }
    }
    __syncthreads();

    // ---- MFMA ----
    const int mrow = wave * 16 + (lane & 15);
    const int kg = lane >> 4;
    half4v a[8];
#pragma unroll
    for (int ks = 0; ks < 8; ks++) {
        const int k0 = ks * 16 + kg * 4;
        const int slot = mrow * 16 + ((k0 >> 3) ^ (mrow & 7));
        a[ks] = *(const half4v*)(smem + slot * 16 + (k0 & 7) * 2);
    }
    f32x4 acc[8];
#pragma unroll
    for (int ct = 0; ct < 8; ct++) acc[ct] = (f32x4){0.f, 0.f, 0.f, 0.f};
#pragma unroll
    for (int ct = 0; ct < 8; ct++) {
        const int c = ct * 16 + (lane & 15);
        const char* sbase = smem + 16384 + c * 256;
        const int csw = c & 7;
#pragma unroll
        for (int ks = 0; ks < 8; ks++) {
            const int k0 = ks * 16 + kg * 4;
            const int slot = (k0 >> 3) ^ csw;
            half4v b = *(const half4v*)(sbase + slot * 16 + (k0 & 7) * 2);
            acc[ct] = __builtin_amdgcn_mfma_f32_16x16x16f16(a[ks], b, acc[ct], 0, 0, 0);
        }
    }

    // ---- AL projections (pre-scaled by log2e) + per-head max ----
    float psh0[4] = {0,0,0,0}, psh1[4] = {0,0,0,0};
    float pdh0[4] = {0,0,0,0}, pdh1[4] = {0,0,0,0};
#pragma unroll
    for (int ct = 0; ct < 8; ct++) {
        const int c = ct * 16 + (lane & 15);
        const float as = asrc[c] * LOG2E, ad = adst[c] * LOG2E;
#pragma unroll
        for (int r = 0; r < 4; r++) {
            if (ct < 4) { psh0[r] = fmaf(acc[ct][r], as, psh0[r]);
                          pdh0[r] = fmaf(acc[ct][r], ad, pdh0[r]); }
            else        { psh1[r] = fmaf(acc[ct][r], as, psh1[r]);
                          pdh1[r] = fmaf(acc[ct][r], ad, pdh1[r]); }
        }
    }
#pragma unroll
    for (int off = 1; off <= 8; off <<= 1) {
#pragma unroll
        for (int r = 0; r < 4; r++) {
            psh0[r] += __shfl_xor(psh0[r], off, 64);
            psh1[r] += __shfl_xor(psh1[r], off, 64);
            pdh0[r] += __shfl_xor(pdh0[r], off, 64);
            pdh1[r] += __shfl_xor(pdh1[r], off, 64);
        }
    }
    float rmax0 = -__builtin_inff(), rmax1 = -__builtin_inff();
    if ((lane & 15) == 0) {
#pragma unroll
        for (int r = 0; r < 4; r++) {
            const int gr = r0 + wave * 16 + (lane >> 4) * 4 + r;
            if (gr < N) {
                ((float4*)AL)[gr] = make_float4(psh0[r], psh1[r], pdh0[r], pdh1[r]);
                rmax0 = fmaxf(rmax0, psh0[r]);
                rmax1 = fmaxf(rmax1, psh1[r]);
            }
        }
    }
#pragma unroll
    for (int off = 32; off > 0; off >>= 1) {
        rmax0 = fmaxf(rmax0, __shfl_xor(rmax0, off, 64));
        rmax1 = fmaxf(rmax1, __shfl_xor(rmax1, off, 64));
    }

    // ---- D -> LDS (reuse staging), then coalesced fp16 write ----
    __syncthreads();
    float* Dst = (float*)smem;
    float* red = (float*)(smem + 33792);
    if (lane == 0) { red[wave * 2] = rmax0; red[wave * 2 + 1] = rmax1; }
#pragma unroll
    for (int ct = 0; ct < 8; ct++) {
        const int col = ct * 16 + (lane & 15);
        float* drow = Dst + wave * 2112 + ((lane >> 4) * 4) * 132 + col;
#pragma unroll
        for (int r = 0; r < 4; r++) drow[r * 132] = acc[ct][r];
    }
    __syncthreads();
    if (t < 2) {
        float m = fmaxf(fmaxf(red[t], red[2 + t]), fmaxf(red[4 + t], red[6 + t]));
        atomicMax(&ubp[t], enc_max(m));
    }
#pragma unroll
    for (int i = 0; i < 4; i++) {
        const int f = t + i * 256;
        const int row = f >> 4, c16 = f & 15;
        if (r0 + row < N) {
            const float* src = Dst + (row >> 4) * 2112 + (row & 15) * 132 + c16 * 8;
            const float4 v0 = *(const float4*)src;
            const float4 v1 = *(const float4*)(src + 4);
            half8v h = { (_Float16)v0.x, (_Float16)v0.y, (_Float16)v0.z, (_Float16)v0.w,
                         (_Float16)v1.x, (_Float16)v1.y, (_Float16)v1.z, (_Float16)v1.w };
            *(half8v*)((_Float16*)H16 + (size_t)(r0 + row) * 128 + c16 * 8) = h;
        }
    }
}

// ---------------------------------------------------------------------------
// CSR build: sliced count -> scan -> finalize -> sliced scatter.
// Edge-list streams use nontemporal i32x4 loads so the slice's cnt/cursor/ssrc
// lines stay L2-resident (full-line writeback instead of 11x amplification).
// ---------------------------------------------------------------------------
__global__ void count_kernel(const int* __restrict__ edst, int* __restrict__ cnt,
                             int E, int N, int sliceN, int bps)
{
    const int slice = blockIdx.x & 7;
    const int dlo = slice * sliceN;
    const int dhi = min(N, dlo + sliceN);
    const int tid = (blockIdx.x >> 3) * 256 + (int)threadIdx.x;
    const int stride = bps * 256;
    const int E4 = E >> 2;
    const i32x4* e4 = (const i32x4*)edst;
    for (int i = tid; i < E4; i += stride) {
        const i32x4 d = __builtin_nontemporal_load(&e4[i]);
        if (d.x >= dlo && d.x < dhi) atomicAdd(&cnt[d.x], 1);
        if (d.y >= dlo && d.y < dhi) atomicAdd(&cnt[d.y], 1);
        if (d.z >= dlo && d.z < dhi) atomicAdd(&cnt[d.z], 1);
        if (d.w >= dlo && d.w < dhi) atomicAdd(&cnt[d.w], 1);
    }
    for (int i = E4 * 4 + tid; i < E + N; i += stride) {
        const int d = (i < E) ? edst[i] : (i - E);   // tail + self loops
        if (d >= dlo && d < dhi) atomicAdd(&cnt[d], 1);
    }
}

__global__ void scan_local_kernel(const int* __restrict__ in, int* __restrict__ out,
                                  int* __restrict__ bsum, int n)
{
    __shared__ int sm[1024];
    const int t = threadIdx.x;
    const int i = blockIdx.x * 1024 + t;
    int v = (i < n) ? in[i] : 0;
    sm[t] = v;
    __syncthreads();
    for (int off = 1; off < 1024; off <<= 1) {
        int x = (t >= off) ? sm[t - off] : 0;
        __syncthreads();
        sm[t] += x;
        __syncthreads();
    }
    if (i < n) out[i] = sm[t];
    if (t == 1023) bsum[blockIdx.x] = sm[t];
}

__global__ void scan_excl_single_kernel(int* __restrict__ a, int B)
{
    __shared__ int sm[1024];
    const int t = threadIdx.x;
    int v = (t < B) ? a[t] : 0;
    sm[t] = v;
    __syncthreads();
    for (int off = 1; off < 1024; off <<= 1) {
        int x = (t >= off) ? sm[t - off] : 0;
        __syncthreads();
        sm[t] += x;
        __syncthreads();
    }
    if (t < B) a[t] = sm[t] - v;   // exclusive
}

__global__ void finalize_csr_kernel(const int* __restrict__ incl,
                                    const int* __restrict__ cnt,
                                    const int* __restrict__ bexcl,
                                    int* __restrict__ dstptr, int* __restrict__ cursor,
                                    int N, int Etot)
{
    const int i = blockIdx.x * 1024 + threadIdx.x;
    if (i < N) {
        int v = incl[i] + bexcl[i >> 10] - cnt[i];
        dstptr[i] = v;
        cursor[i] = v;
    }
    if (i == N) dstptr[N] = Etot;
}

__global__ void scatter_kernel(const int* __restrict__ esrc, const int* __restrict__ edst,
                               int* __restrict__ cursor, int* __restrict__ ssrc,
                               int E, int N, int sliceN, int bps)
{
    const int slice = blockIdx.x & 7;
    const int dlo = slice * sliceN;
    const int dhi = min(N, dlo + sliceN);
    const int tid = (blockIdx.x >> 3) * 256 + (int)threadIdx.x;
    const int stride = bps * 256;
    const int E4 = E >> 2;
    const i32x4* s4p = (const i32x4*)esrc;
    const i32x4* d4p = (const i32x4*)edst;
    for (int i = tid; i < E4; i += stride) {
        const i32x4 d = __builtin_nontemporal_load(&d4p[i]);
        const i32x4 s = __builtin_nontemporal_load(&s4p[i]);
        if (d.x >= dlo && d.x < dhi) ssrc[atomicAdd(&cursor[d.x], 1)] = s.x;
        if (d.y >= dlo && d.y < dhi) ssrc[atomicAdd(&cursor[d.y], 1)] = s.y;
        if (d.z >= dlo && d.z < dhi) ssrc[atomicAdd(&cursor[d.z], 1)] = s.z;
        if (d.w >= dlo && d.w < dhi) ssrc[atomicAdd(&cursor[d.w], 1)] = s.w;
    }
    for (int i = E4 * 4 + tid; i < E + N; i += stride) {
        int s, d;
        if (i < E) { s = esrc[i]; d = edst[i]; }
        else       { s = d = i - E; }                // self loops
        if (d >= dlo && d < dhi) ssrc[atomicAdd(&cursor[d], 1)] = s;
    }
}

// ---------------------------------------------------------------------------
// Aggregation, shifted softmax in exp2 domain. TWO nodes per wave (lanes
// 0-31 node A, 32-63 node B); lane owns 4 channels (uint2 = 8B gathers);
// head = nl>>4. Mov-free 3-slot ring over 4-edge blocks.
// Masked slots clamp src to row 0 (always L2-hot) and zero p via rem mask.
// mode 0: out[n,128] = ELU(acc/s + b)   mode 1: out[n,64] = mean_h(acc/s)+b
// ---------------------------------------------------------------------------
__global__ __launch_bounds__(256) void aggregate_kernel(
    const __half* __restrict__ H16, const float* __restrict__ AL,
    const int* __restrict__ dstptr, const int* __restrict__ ssrc,
    const unsigned* __restrict__ ubenc, const float* __restrict__ bias,
    float* __restrict__ out, int N, int mode)
{
    const int wid  = (blockIdx.x * blockDim.x + threadIdx.x) >> 6;
    const int lane = threadIdx.x & 63;
    if (wid * 2 >= N) return;
    const int n    = wid * 2 + (lane >> 5);
    const bool act = (n < N);
    const int nn   = act ? n : (N - 1);
    const int beg  = dstptr[nn];
    const int edges = act ? (dstptr[nn + 1] - beg) : 0;
    const int nl   = lane & 31;
    const int head = nl >> 4;

    const float ald = AL[(size_t)nn * 4 + 2 + head];
    float ub = dec_max(ubenc[head]) + ald;
    ub = fmaxf(ub, NEG_SLOPE * ub);           // leaky, scale-invariant

    int tr = (edges + 3) >> 2;
    tr = max(tr, __shfl_xor(tr, 32, 64));
    const int trips = tr;

    float s = 0.f, a0 = 0.f, a1 = 0.f, a2 = 0.f, a3 = 0.f;

    int   sv0[4], sv1[4], sv2[4];
    float e0[4], e1[4], e2[4];
    uint2 g0[4], g1[4], g2[4];

    auto LSRC = [&](int b, int (&sv)[4]) {
#pragma unroll
        for (int k = 0; k < 4; k++) {
            const int idx = 4 * b + k;
            const int v = ssrc[beg + idx];    // padded: safe
            sv[k] = (idx < edges) ? v : 0;    // clamp masked -> hot row 0
        }
    };
    auto LHE = [&](const int (&sv)[4], float (&e)[4], uint2 (&g)[4]) {
#pragma unroll
        for (int k = 0; k < 4; k++) {
            e[k] = AL[(size_t)sv[k] * 4 + head];
            g[k] = ((const uint2*)(H16 + (size_t)sv[k] * 128))[nl];
        }
    };
    auto COMP = [&](int t, const float (&e)[4], const uint2 (&g)[4]) {
        const int rem = edges - 4 * t;        // <=0 for overflow/inactive
#pragma unroll
        for (int k = 0; k < 4; k++) {
            float tt = e[k] + ald;
            tt = fmaxf(tt, NEG_SLOPE * tt);   // leaky (logits pre-scaled)
            float p = exp2f(tt - ub);
            p = (k < rem) ? p : 0.f;          // mask
            s += p;
            const __half2* ph = (const __half2*)&g[k];
            const float2 f01 = __half22float2(ph[0]);
            const float2 f23 = __half22float2(ph[1]);
            a0 = fmaf(p, f01.x, a0);
            a1 = fmaf(p, f01.y, a1);
            a2 = fmaf(p, f23.x, a2);
            a3 = fmaf(p, f23.y, a3);
        }
    };

    // prologue: srcs for blocks 0..2; gathers for blocks 0,1 in flight
    LSRC(0, sv0); LSRC(1, sv1); LSRC(2, sv2);
    LHE(sv0, e0, g0);
    LHE(sv1, e1, g1);

    for (int t = 0; t < trips; ) {
        LHE(sv2, e2, g2); LSRC(t + 3, sv0); COMP(t, e0, g0); if (++t == trips) break;
        LHE(sv0, e0, g0); LSRC(t + 3, sv1); COMP(t, e1, g1); if (++t == trips) break;
        LHE(sv1, e1, g1); LSRC(t + 3, sv2); COMP(t, e2, g2); if (++t == trips) break;
    }

    if (!act) return;
    const float inv = 1.f / s;                // s > 0 (self loop)
    float o0 = a0 * inv, o1 = a1 * inv, o2 = a2 * inv, o3 = a3 * inv;

    if (mode == 0) {
        const float4 b4 = ((const float4*)bias)[nl];
        o0 += b4.x; o1 += b4.y; o2 += b4.z; o3 += b4.w;
        o0 = (o0 > 0.f) ? o0 : (__expf(o0) - 1.f);
        o1 = (o1 > 0.f) ? o1 : (__expf(o1) - 1.f);
        o2 = (o2 > 0.f) ? o2 : (__expf(o2) - 1.f);
        o3 = (o3 > 0.f) ? o3 : (__expf(o3) - 1.f);
        ((float4*)out)[(size_t)n * 32 + nl] = make_float4(o0, o1, o2, o3);
    } else {
        const float q0 = __shfl_xor(o0, 16, 64);   // head partner within node
        const float q1 = __shfl_xor(o1, 16, 64);
        const float q2 = __shfl_xor(o2, 16, 64);
        const float q3 = __shfl_xor(o3, 16, 64);
        if (nl < 16) {
            const float4 b4 = ((const float4*)bias)[nl];
            ((float4*)out)[(size_t)n * 16 + nl] =
                make_float4(0.5f * (o0 + q0) + b4.x, 0.5f * (o1 + q1) + b4.y,
                            0.5f * (o2 + q2) + b4.z, 0.5f * (o3 + q3) + b4.w);
        }
    }
}

// ---------------------------------------------------------------------------
extern "C" void kernel_launch(void* const* d_in, const int* in_sizes, int n_in,
                              void* d_out, int out_size, void* d_ws, size_t ws_size,
                              hipStream_t stream)
{
    const float* x   = (const float*)d_in[0];
    const int*   eix = (const int*)d_in[1];   // [2, E] int32
    const float* W1  = (const float*)d_in[2];
    const float* as1 = (const float*)d_in[3];
    const float* ad1 = (const float*)d_in[4];
    const float* b1  = (const float*)d_in[5];
    const float* W2  = (const float*)d_in[6];
    const float* as2 = (const float*)d_in[7];
    const float* ad2 = (const float*)d_in[8];
    const float* b2  = (const float*)d_in[9];
    float* out = (float*)d_out;

    const int N = in_sizes[0] / 128;
    const int E = in_sizes[1] / 2;
    const int Etot = E + N;
    const int* esrc = eix;
    const int* edst = eix + E;

    // ---- workspace layout (~87 MB) ----
    char* p = (char*)d_ws;
    __half*    h16    = (__half*)p;    p += (size_t)N * 128 * 2;
    float*     y1     = (float*)p;     p += (size_t)N * 128 * 4;
    float*     al     = (float*)p;     p += (size_t)N * 4 * 4;
    int*       cnt    = (int*)p;       p += (size_t)N * 4;
    unsigned*  ub     = (unsigned*)p;  p += 64;                // [0..1] L1, [2..3] L2
    _Float16*  wt     = (_Float16*)p;  p += 32768 * 2;         // 2 layers W^T fp16
    int*       incl   = (int*)p;       p += (size_t)N * 4;
    int*       dstptr = (int*)p;       p += (size_t)(N + 1) * 4;
    int*       cursor = (int*)p;       p += (size_t)N * 4;
    int*       bs1    = (int*)p;       p += 1024 * 4;
    int*       ssrc   = (int*)p;       p += (size_t)(Etot + 256) * 4;  // pipeline pad

    hipMemsetAsync(cnt, 0, (size_t)N * 4 + 64, stream);      // cnt + ub
    hipMemsetAsync(ssrc + Etot, 0, 256 * 4, stream);         // zero tail pad

    // ---- one-time prep + CSR (shared by both layers) ----
    wprep_kernel<<<128, 256, 0, stream>>>(W1, W2, wt);
    {
        const int B0 = (N + 1023) / 1024;
        const int sliceN = (N + 7) / 8;
        const int bps = 512;
        count_kernel<<<bps * 8, 256, 0, stream>>>(edst, cnt, E, N, sliceN, bps);
        scan_local_kernel<<<B0, 1024, 0, stream>>>(cnt, incl, bs1, N);
        scan_excl_single_kernel<<<1, 1024, 0, stream>>>(bs1, B0);
        finalize_csr_kernel<<<(N + 1024) / 1024, 1024, 0, stream>>>(
            incl, cnt, bs1, dstptr, cursor, N, Etot);
        scatter_kernel<<<bps * 8, 256, 0, stream>>>(esrc, edst, cursor, ssrc,
                                                    E, N, sliceN, bps);
    }

    const int ggrid = (N + 63) / 64;                   // 64 rows/block (MFMA)
    const int ablocks = (N + 7) / 8;                   // 8 nodes per 256-thr block

    // ---- Layer 1 ----
    gemm_al_kernel<<<ggrid, 256, 0, stream>>>(x, wt, as1, ad1, h16, al, ub, N);
    aggregate_kernel<<<ablocks, 256, 0, stream>>>(h16, al, dstptr, ssrc, ub, b1, y1, N, 0);

    // ---- Layer 2 ----
    gemm_al_kernel<<<ggrid, 256, 0, stream>>>(y1, wt + 16384, as2, ad2, h16, al, ub + 2, N);
    aggregate_kernel<<<ablocks, 256, 0, stream>>>(h16, al, dstptr, ssrc, ub + 2, b2, out, N, 1);
}